// Round 1
// 69.265 us; speedup vs baseline: 1.0037x; 1.0037x over previous
//
#include <hip/hip_runtime.h>

#define N 4096
#define EPS 1e-8f
#define BLK 512           // threads per block (8 waves)
#define APB 8             // agents per block; grid = N/APB = 512 blocks

typedef float v2f __attribute__((ext_vector_type(2)));

// ---------------------------------------------------------------------------
// Single fused kernel: repulsion + attraction + propagation + cost.
// No workspace, no second launch. Each block owns 8 agents; all 4096 agent
// positions staged once into LDS (32 KB, SoA). Thread (il=tid&3, ks=tid>>2)
// accumulates 2 agents over a 32-j slice (2-agent amortization halves LDS
// traffic per pair). Chunk-rotated slice traversal keeps ds_read_b128
// conflicts at 2-way (free). Every block redundantly computes agent 0's
// propagated position p0 (needed by all costs) -> no cross-block dependency.
// ---------------------------------------------------------------------------
__global__ __launch_bounds__(BLK) void fused(const float4* __restrict__ state4,
                                             const float*  __restrict__ cost_in,
                                             const float*  __restrict__ goals,
                                             const float*  __restrict__ rip,
                                             const float4* __restrict__ obs4,
                                             float*        __restrict__ out) {
    __shared__ float  sx[N];
    __shared__ float  sy[N];
    __shared__ float4 red[BLK / 64][4];   // per-wave, per agent-pair (FxA,FyA,FxB,FyB)
    __shared__ float2 red0[BLK / 64];     // per-wave agent-0 partial

    const int tid = threadIdx.x;
    const int blk = blockIdx.x;

    // ---- stage all positions to LDS (SoA), b64 LDS writes ----
#pragma unroll
    for (int m = 0; m < 4; ++m) {
        const int j0 = 2 * tid + 1024 * m;
        const float4 a = state4[j0];
        const float4 b = state4[j0 + 1];
        *(v2f*)&sx[j0] = (v2f){a.x, b.x};
        *(v2f*)&sy[j0] = (v2f){a.y, b.y};
    }

    const int il = tid & 3;               // agent-pair id within block
    const int ks = tid >> 2;              // slice id 0..127 (32 j's each)
    const int a0 = blk * APB + 2 * il;    // this thread's agents: a0, a0+1
    const float4 sA = state4[a0];
    const float4 sB = state4[a0 + 1];
    __syncthreads();

    // coef(d) = ALPHA*exp((2R-d)/BETTA)/d = exp2(C0 - C1*d)/d
    const float C1 = 1.44269504088896340736f / 0.71f;   // log2e/BETTA
    const float C0 = 0.6f * C1 + 3.41414351f;           // 2R*C1 + log2(ALPHA)

    const v2f eps2 = {EPS, EPS};
    const v2f xA = {sA.x, sA.x}, yA = {sA.y, sA.y};
    const v2f xB = {sB.x, sB.x}, yB = {sB.y, sB.y};
    v2f fxA = {0.f, 0.f}, fyA = {0.f, 0.f};
    v2f fxB = {0.f, 0.f}, fyB = {0.f, 0.f};

    // ---- main loop: 8 chunks of 4 j's, rotated by ks to spread banks ----
#pragma unroll
    for (int c = 0; c < 8; ++c) {
        const int j0 = (ks << 5) + (((c + ks) & 7) << 2);
        const float4 X = *(const float4*)&sx[j0];   // ds_read_b128
        const float4 Y = *(const float4*)&sy[j0];
        const v2f Xp[2] = {{X.x, X.y}, {X.z, X.w}};
        const v2f Yp[2] = {{Y.x, Y.y}, {Y.z, Y.w}};
#pragma unroll
        for (int h = 0; h < 2; ++h) {
            {   // agent A
                const v2f dx = xA - Xp[h];
                const v2f dy = yA - Yp[h];
                const v2f r2 = dx * dx + (dy * dy + eps2);
                v2f inv; inv.x = __builtin_amdgcn_rsqf(r2.x);
                         inv.y = __builtin_amdgcn_rsqf(r2.y);
                const v2f d   = r2 * inv;
                const v2f arg = C0 - C1 * d;
                v2f e; e.x = __builtin_amdgcn_exp2f(arg.x);
                       e.y = __builtin_amdgcn_exp2f(arg.y);
                const v2f coef = e * inv;
                fxA += coef * dx;    // i==j: dx=dy=0 -> exact 0 (eye mask)
                fyA += coef * dy;
            }
            {   // agent B
                const v2f dx = xB - Xp[h];
                const v2f dy = yB - Yp[h];
                const v2f r2 = dx * dx + (dy * dy + eps2);
                v2f inv; inv.x = __builtin_amdgcn_rsqf(r2.x);
                         inv.y = __builtin_amdgcn_rsqf(r2.y);
                const v2f d   = r2 * inv;
                const v2f arg = C0 - C1 * d;
                v2f e; e.x = __builtin_amdgcn_exp2f(arg.x);
                       e.y = __builtin_amdgcn_exp2f(arg.y);
                const v2f coef = e * inv;
                fxB += coef * dx;
                fyB += coef * dy;
            }
        }
    }

    // ---- redundant agent-0 force: thread t covers j = t + 512m (coalesced banks) ----
    float f0x = 0.f, f0y = 0.f;
    {
        const float x0 = sx[0], y0 = sy[0];     // LDS broadcast
#pragma unroll
        for (int m = 0; m < 8; ++m) {
            const int j = tid + (m << 9);
            const float dx = x0 - sx[j];
            const float dy = y0 - sy[j];
            const float r2 = fmaf(dx, dx, fmaf(dy, dy, EPS));
            const float inv = __builtin_amdgcn_rsqf(r2);
            const float d   = r2 * inv;
            const float coef = __builtin_amdgcn_exp2f(fmaf(-C1, d, C0)) * inv;
            f0x = fmaf(coef, dx, f0x);
            f0y = fmaf(coef, dy, f0y);
        }
    }

    // ---- reduce: horizontal v2f sums, then xor-butterfly over ks within wave ----
    float FxA = fxA.x + fxA.y, FyA = fyA.x + fyA.y;
    float FxB = fxB.x + fxB.y, FyB = fyB.x + fyB.y;
#pragma unroll
    for (int off = 4; off <= 32; off <<= 1) {
        FxA += __shfl_xor(FxA, off);
        FyA += __shfl_xor(FyA, off);
        FxB += __shfl_xor(FxB, off);
        FyB += __shfl_xor(FyB, off);
    }
#pragma unroll
    for (int off = 1; off <= 32; off <<= 1) {
        f0x += __shfl_xor(f0x, off);
        f0y += __shfl_xor(f0y, off);
    }
    const int wv = tid >> 6, ln = tid & 63;
    if (ln < 4)  red[wv][ln] = make_float4(FxA, FyA, FxB, FyB);
    if (ln == 0) red0[wv] = make_float2(f0x, f0y);
    __syncthreads();

    // ---- finalize: threads 0..7, one agent each; each recomputes p0 identically ----
    if (tid < APB) {
        float Fx = 0.f, Fy = 0.f, F0x = 0.f, F0y = 0.f;
#pragma unroll
        for (int w = 0; w < BLK / 64; ++w) {
            const float4 r = red[w][tid >> 1];
            Fx += (tid & 1) ? r.z : r.x;
            Fy += (tid & 1) ? r.w : r.y;
            const float2 r0 = red0[w];
            F0x += r0.x; F0y += r0.y;
        }

        // agent 0: attraction + propagation -> p0 (bitwise-identical on all threads/blocks)
        const float4 s0 = state4[0];
        const float g0x = goals[0] - s0.x, g0y = goals[1] - s0.y;
        const float gd0 = sqrtf(fmaf(g0x, g0x, fmaf(g0y, g0y, EPS)));
        F0x += 120.f * (1.34f * g0x / gd0 - s0.z);      // K*MASS = 120
        F0y += 120.f * (1.34f * g0y / gd0 - s0.w);
        float v0x = fmaf(F0x, 0.4f / 60.f, s0.z);
        float v0y = fmaf(F0y, 0.4f / 60.f, s0.w);
        const float sp0 = sqrtf(fmaf(v0x, v0x, fmaf(v0y, v0y, EPS)));
        const float fc0 = fminf(1.f, 1.34f / sp0);
        v0x *= fc0; v0y *= fc0;
        const float p0x = fmaf(v0x, 0.4f, s0.x);
        const float p0y = fmaf(v0y, 0.4f, s0.y);

        // own agent: attraction + propagation
        const int ia = blk * APB + tid;
        const float4 s = state4[ia];
        const float gx = goals[2 * ia]     - s.x;
        const float gy = goals[2 * ia + 1] - s.y;
        const float gd = sqrtf(fmaf(gx, gx, fmaf(gy, gy, EPS)));
        Fx += 120.f * (1.34f * gx / gd - s.z);
        Fy += 120.f * (1.34f * gy / gd - s.w);
        float vnx = fmaf(Fx, 0.4f / 60.f, s.z);
        float vny = fmaf(Fy, 0.4f / 60.f, s.w);
        const float sp = sqrtf(fmaf(vnx, vnx, fmaf(vny, vny, EPS)));
        const float fc = fminf(1.f, 1.34f / sp);
        vnx *= fc; vny *= fc;
        const float pnx = fmaf(vnx, 0.4f, s.x);
        const float pny = fmaf(vny, 0.4f, s.y);
        ((float4*)out)[ia] = make_float4(pnx, pny, vnx, vny);

        // cost
        const float rx = rip[0], ry = rip[1];
        const float gvx = goals[0] - rx, gvy = goals[1] - ry;
        const float inv_gl = 1.f / (sqrtf(gvx * gvx + gvy * gvy) + EPS);
        const float pg = ((p0x - rx) * gvx + (p0y - ry) * gvy) * inv_gl;
        const float ddx = pnx - p0x, ddy = pny - p0y;
        const float dist_rp = sqrtf(fmaf(ddx, ddx, fmaf(ddy, ddy, EPS)));
        const float blame = __expf(-dist_rp);
        const float4 ob = obs4[ia];
        const float dev = (pnx - ob.x) * (pnx - ob.x) + (pny - ob.y) * (pny - ob.y);
        out[4 * N + ia] = cost_in[ia] + (-pg + blame + dev);
    }
}

extern "C" void kernel_launch(void* const* d_in, const int* in_sizes, int n_in,
                              void* d_out, int out_size, void* d_ws, size_t ws_size,
                              hipStream_t stream) {
    const float* state = (const float*)d_in[0];
    const float* cost  = (const float*)d_in[1];
    const float* goals = (const float*)d_in[2];
    const float* rip   = (const float*)d_in[3];
    const float* obs   = (const float*)d_in[4];
    float* out = (float*)d_out;
    (void)d_ws; (void)ws_size;   // workspace deliberately untouched

    fused<<<N / APB, BLK, 0, stream>>>((const float4*)state, cost, goals, rip,
                                       (const float4*)obs, out);
}